// Round 5
// baseline (413.949 us; speedup 1.0000x reference)
//
#include <hip/hip_runtime.h>
#include <hip/hip_cooperative_groups.h>
#include <hip/hip_bf16.h>
#include <string.h>

#define B_ 8
#define N_ 50000
#define F_ 32
#define S_ 16
#define O_ 64
#define K_ (F_ * S_)            // 512
#define XELEMS (B_ * N_ * F_)   // 12.8M
#define TPB (N_ / 16)           // 3125 tiles per batch
#define BPB 196                 // work-groups per batch (196*16 = 3136 >= 3125)
#define GRID_COOP 512           // exactly 2 blocks/CU co-resident (64 KB LDS each)

typedef __attribute__((ext_vector_type(8))) short bf16x8;
typedef __attribute__((ext_vector_type(4))) float f32x4;
typedef __attribute__((ext_vector_type(4))) int int4v;

union bfpack { bf16x8 v; __hip_bfloat16 h[8]; };

// ================= shared spiral body (r4's 94 us structure, verbatim) ==========
// LDS-DMA deep pipeline: gathers via global_load_lds into a per-wave 4-slot ring
// (no dest VGPRs -> depth is structural), pinned issue order, counted vmcnt.
__device__ __forceinline__ void spiral_body(
        const unsigned short* __restrict__ xb, const int* __restrict__ adj,
        const unsigned short* __restrict__ Wb, const float* __restrict__ bias,
        float* __restrict__ out, unsigned char* ringw,
        int b, int tib0, int lane, int m16, int quad)
{
    int rowbase[4], nn[4];
#pragma unroll
    for (int vt = 0; vt < 4; ++vt) {
        int t = tib0 + vt;
        if (t >= TPB) t = TPB - 1; // clamp: duplicate identical stores, benign
        nn[vt] = t * 16;
        rowbase[vt] = b * N_ + t * 16;
    }
    const size_t xbase = (size_t)b * N_ * F_;

    // All adj up front (nt: read-once stream). 16 x int4.
    int4v aj_all[4][4]; // [vt][kt4]
#pragma unroll
    for (int vt = 0; vt < 4; ++vt)
#pragma unroll
        for (int kt4 = 0; kt4 < 4; ++kt4)
            aj_all[vt][kt4] = __builtin_nontemporal_load(
                (const int4v*)(adj + (size_t)(rowbase[vt] + m16) * S_ + kt4 * 4));

    f32x4 acc[4][4];
#pragma unroll
    for (int vt = 0; vt < 4; ++vt)
#pragma unroll
        for (int nt = 0; nt < 4; ++nt)
            acc[vt][nt] = (f32x4){0.f, 0.f, 0.f, 0.f};

    bf16x8 wfp[4][4]; // W fragment pipeline: [ring slot][nt], static indices only

#define GATHER_ISSUE(g_)                                                                   \
    do {                                                                                   \
        if ((g_) < 16) {                                                                   \
            const int kt4_ = (g_) >> 2, q_ = (g_) & 3;                                     \
            _Pragma("unroll")                                                              \
            for (int vt = 0; vt < 4; ++vt) {                                               \
                int a_ = aj_all[vt][kt4_][q_];                                             \
                const unsigned short* src_ = xb + xbase + (size_t)a_ * F_ + quad * 8;      \
                __builtin_amdgcn_global_load_lds(                                          \
                    (const __attribute__((address_space(1))) void*)src_,                   \
                    (__attribute__((address_space(3))) void*)(ringw + ((((g_) & 3) * 4 + vt) << 10)), \
                    16, 0, 0);                                                             \
            }                                                                              \
        }                                                                                  \
    } while (0)

#define LOAD_W(g_)                                                                         \
    do {                                                                                   \
        if ((g_) < 16) {                                                                   \
            _Pragma("unroll")                                                              \
            for (int nt = 0; nt < 4; ++nt)                                                 \
                wfp[(g_) & 3][nt] = *(const bf16x8*)(                                      \
                    Wb + (size_t)(((g_) * 4 + quad) * 64 + nt * 16 + m16) * 8);            \
        }                                                                                  \
    } while (0)

#define SB __builtin_amdgcn_sched_barrier(0)

    // Prologue FIFO: C0 W0 C1 W1 C2 W2 (24 vmem in flight; earlier adj loads
    // drain first under the same counted waits — in-order retirement).
    GATHER_ISSUE(0); SB; LOAD_W(0); SB;
    GATHER_ISSUE(1); SB; LOAD_W(1); SB;
    GATHER_ISSUE(2); SB; LOAD_W(2); SB;

#pragma unroll
    for (int g = 0; g < 16; ++g) {
        GATHER_ISSUE(g + 3); SB;
        LOAD_W(g + 3); SB;
        if (g < 13)       asm volatile("s_waitcnt vmcnt(24)" ::: "memory");
        else if (g == 13) asm volatile("s_waitcnt vmcnt(16)" ::: "memory");
        else if (g == 14) asm volatile("s_waitcnt vmcnt(8)"  ::: "memory");
        else              asm volatile("s_waitcnt vmcnt(0)"  ::: "memory");
        SB;
        bf16x8 xf[4];
#pragma unroll
        for (int vt = 0; vt < 4; ++vt)
            xf[vt] = *(const bf16x8*)(ringw + (((g & 3) * 4 + vt) << 10) + lane * 16);
#pragma unroll
        for (int vt = 0; vt < 4; ++vt)
#pragma unroll
            for (int nt = 0; nt < 4; ++nt)
                acc[vt][nt] = __builtin_amdgcn_mfma_f32_16x16x32_bf16(wfp[g & 3][nt], xf[vt], acc[vt][nt], 0, 0, 0);
        SB;
    }
#undef GATHER_ISSUE
#undef LOAD_W
#undef SB

    // Epilogue: cached stores (WRITE_SIZE exact at ~100 MB in r0/r4).
#pragma unroll
    for (int vt = 0; vt < 4; ++vt) {
        const int n = nn[vt] + m16;
        const bool zero = (n == N_ - 1);
        float* orow = out + (size_t)(rowbase[vt] + m16) * O_ + quad * 4;
#pragma unroll
        for (int nt = 0; nt < 4; ++nt) {
            f32x4 bv = *(const f32x4*)(bias + nt * 16 + quad * 4);
            f32x4 v;
#pragma unroll
            for (int r = 0; r < 4; ++r) {
                float t = acc[vt][nt][r] + bv[r];
                t = t > 0.f ? t : (__expf(t) - 1.f); // ELU alpha=1
                v[r] = zero ? 0.f : t;
            }
            *(f32x4*)(orow + nt * 16) = v;
        }
    }
}

// ================= fused cooperative kernel: prep + grid.sync + spiral ==========
// 512 blocks (2/CU). Prep phase: W->Wb + x->xb (grid-stride). Spiral phase:
// 1568 groups grabbed dynamically from 8 per-batch counters (keeps batch<->XCD
// affinity, r4-equivalent balance). Counters never reset: each block reads its
// batch counter BEFORE any grabs (pre-sync) and grabs relative to that base.
__global__ __launch_bounds__(256, 2) void fused_kernel(
        const float* __restrict__ x, const int* __restrict__ adj,
        const float* __restrict__ W, const float* __restrict__ bias,
        float* __restrict__ out, unsigned short* __restrict__ Wb,
        unsigned short* __restrict__ xb, unsigned int* __restrict__ ctr)
{
    __shared__ __align__(16) unsigned char ring[4][4][4][1024]; // 64 KB
    __shared__ unsigned int sh_base, sh_g;

    const int tid = threadIdx.x;
    const unsigned gid = blockIdx.x * 256u + (unsigned)tid;
    const int b = blockIdx.x & 7; // batch == intended XCD (blocks round-robin XCDs)

    if (tid == 0) sh_base = ctr[b]; // safe: no grabs until after grid sync

    // --- prep: W -> bf16 fragment-swizzled (first 128 blocks, 1 elem/thread) ---
    if (gid < (unsigned)(O_ * K_)) {
        int j = gid & 7, o = (gid >> 3) & 63, qk = gid >> 9;
        int quad_ = qk & 3, kt = qk >> 2;
        __hip_bfloat16 h = __float2bfloat16(W[o * K_ + kt * 32 + quad_ * 8 + j]);
        unsigned short u; memcpy(&u, &h, 2);
        Wb[gid] = u;
    }
    // --- prep: x -> bf16 rows, grid-stride (13 iters over 1.6M 8-elem units) ---
    for (unsigned i = gid; i < (unsigned)(XELEMS / 8); i += GRID_COOP * 256u) {
        size_t base = (size_t)i * 8;
        f32x4 a = __builtin_nontemporal_load((const f32x4*)(x + base));
        f32x4 c = __builtin_nontemporal_load((const f32x4*)(x + base + 4));
        bfpack p;
        p.h[0] = __float2bfloat16(a[0]); p.h[1] = __float2bfloat16(a[1]);
        p.h[2] = __float2bfloat16(a[2]); p.h[3] = __float2bfloat16(a[3]);
        p.h[4] = __float2bfloat16(c[0]); p.h[5] = __float2bfloat16(c[1]);
        p.h[6] = __float2bfloat16(c[2]); p.h[7] = __float2bfloat16(c[3]);
        *(bf16x8*)(xb + base) = p.v;
    }
    __threadfence(); // device-scope release of xb/Wb before grid barrier
    cooperative_groups::this_grid().sync();

    // --- spiral phase ---
    const int lane = tid & 63, wv = tid >> 6;
    const int m16 = lane & 15, quad = lane >> 4;
    unsigned char* ringw = &ring[wv][0][0][0];

    for (;;) {
        __syncthreads(); // order sh_g reuse across iterations (drains nothing extra: body ends vmcnt(0))
        if (tid == 0) sh_g = atomicAdd(&ctr[b], 1u) - sh_base;
        __syncthreads();
        unsigned g = sh_g;
        if (g >= (unsigned)BPB) break;
        spiral_body(xb, adj, Wb, bias, out, ringw, b, ((int)g * 4 + wv) * 4, lane, m16, quad);
    }
}

// ================= fallback path A: r4's two-kernel pipeline ====================
__global__ __launch_bounds__(256) void prep_kernel(const float* __restrict__ W,
                                                   unsigned short* __restrict__ Wb,
                                                   const float* __restrict__ x,
                                                   unsigned short* __restrict__ xb) {
    int bid = blockIdx.x;
    if (bid < 128) {
        int i = bid * 256 + threadIdx.x;
        int j = i & 7, o = (i >> 3) & 63, qk = i >> 9;
        int quad = qk & 3, kt = qk >> 2;
        __hip_bfloat16 h = __float2bfloat16(W[o * K_ + kt * 32 + quad * 8 + j]);
        unsigned short u; memcpy(&u, &h, 2);
        Wb[i] = u;
    } else {
        int i = (bid - 128) * 256 + threadIdx.x;
        if (i < XELEMS / 8) {
            size_t base = (size_t)i * 8;
            f32x4 a = __builtin_nontemporal_load((const f32x4*)(x + base));
            f32x4 c = __builtin_nontemporal_load((const f32x4*)(x + base + 4));
            bfpack p;
            p.h[0] = __float2bfloat16(a[0]); p.h[1] = __float2bfloat16(a[1]);
            p.h[2] = __float2bfloat16(a[2]); p.h[3] = __float2bfloat16(a[3]);
            p.h[4] = __float2bfloat16(c[0]); p.h[5] = __float2bfloat16(c[1]);
            p.h[6] = __float2bfloat16(c[2]); p.h[7] = __float2bfloat16(c[3]);
            *(bf16x8*)(xb + base) = p.v;
        }
    }
}

__global__ __launch_bounds__(256, 2) void spiral_kernel(
        const unsigned short* __restrict__ xb, const int* __restrict__ adj,
        const unsigned short* __restrict__ Wb, const float* __restrict__ bias,
        float* __restrict__ out) {
    __shared__ __align__(16) unsigned char ring[4][4][4][1024];
    const int lane = threadIdx.x & 63;
    const int wv   = threadIdx.x >> 6;
    const int m16  = lane & 15;
    const int quad = lane >> 4;
    const int b  = blockIdx.x & 7;
    const int jb = blockIdx.x >> 3;
    spiral_body(xb, adj, Wb, bias, out, &ring[wv][0][0][0],
                b, (jb * 4 + wv) * 4, lane, m16, quad);
}

// ================= fallback path B (tiny ws): fp32-gather kernel ================
__global__ __launch_bounds__(256) void wconv_kernel(const float* __restrict__ W,
                                                    unsigned short* __restrict__ Wb) {
    int i = blockIdx.x * 256 + threadIdx.x;
    if (i < O_ * K_) {
        int j = i & 7, o = (i >> 3) & 63, qk = i >> 9;
        int quad = qk & 3, kt = qk >> 2;
        __hip_bfloat16 h = __float2bfloat16(W[o * K_ + kt * 32 + quad * 8 + j]);
        unsigned short u; memcpy(&u, &h, 2);
        Wb[i] = u;
    }
}

__global__ __launch_bounds__(256) void spiral_f32_kernel(
        const float* __restrict__ x, const int* __restrict__ adj,
        const unsigned short* __restrict__ Wb, const float* __restrict__ bias,
        float* __restrict__ out) {
    const int lane = threadIdx.x & 63;
    const int wv = threadIdx.x >> 6;
    const int m16 = lane & 15, quad = lane >> 4;
    const int b  = blockIdx.x & 7;
    const int jb = blockIdx.x >> 3;
    const int tib0 = (jb * 4 + wv) * 4;
    int rowbase[4], nn[4];
#pragma unroll
    for (int vt = 0; vt < 4; ++vt) {
        int t = tib0 + vt;
        if (t >= TPB) t = TPB - 1;
        nn[vt] = t * 16;
        rowbase[vt] = b * N_ + t * 16;
    }
    f32x4 acc[4][4];
#pragma unroll
    for (int vt = 0; vt < 4; ++vt)
#pragma unroll
        for (int nt = 0; nt < 4; ++nt) acc[vt][nt] = (f32x4){0.f,0.f,0.f,0.f};
    for (int kt = 0; kt < 16; ++kt) {
        bf16x8 wf[4];
#pragma unroll
        for (int nt = 0; nt < 4; ++nt)
            wf[nt] = *(const bf16x8*)(Wb + (size_t)((kt * 4 + quad) * 64 + nt * 16 + m16) * 8);
#pragma unroll
        for (int vt = 0; vt < 4; ++vt) {
            int a = adj[(size_t)(rowbase[vt] + m16) * S_ + kt];
            const float* xr = x + ((size_t)b * N_ + a) * F_ + quad * 8;
            f32x4 x0 = *(const f32x4*)xr;
            f32x4 x1 = *(const f32x4*)(xr + 4);
            bfpack af;
            af.h[0]=__float2bfloat16(x0[0]); af.h[1]=__float2bfloat16(x0[1]);
            af.h[2]=__float2bfloat16(x0[2]); af.h[3]=__float2bfloat16(x0[3]);
            af.h[4]=__float2bfloat16(x1[0]); af.h[5]=__float2bfloat16(x1[1]);
            af.h[6]=__float2bfloat16(x1[2]); af.h[7]=__float2bfloat16(x1[3]);
#pragma unroll
            for (int nt = 0; nt < 4; ++nt)
                acc[vt][nt] = __builtin_amdgcn_mfma_f32_16x16x32_bf16(wf[nt], af.v, acc[vt][nt], 0, 0, 0);
        }
    }
#pragma unroll
    for (int vt = 0; vt < 4; ++vt) {
        const int n = nn[vt] + m16;
        const bool zero = (n == N_ - 1);
        float* orow = out + (size_t)(rowbase[vt] + m16) * O_ + quad * 4;
#pragma unroll
        for (int nt = 0; nt < 4; ++nt) {
            f32x4 bv = *(const f32x4*)(bias + nt * 16 + quad * 4);
            f32x4 v;
#pragma unroll
            for (int r = 0; r < 4; ++r) {
                float t = acc[vt][nt][r] + bv[r];
                t = t > 0.f ? t : (__expf(t) - 1.f);
                v[r] = zero ? 0.f : t;
            }
            *(f32x4*)(orow + nt * 16) = v;
        }
    }
}

extern "C" void kernel_launch(void* const* d_in, const int* in_sizes, int n_in,
                              void* d_out, int out_size, void* d_ws, size_t ws_size,
                              hipStream_t stream) {
    const float* x    = (const float*)d_in[0];
    const int*   adj  = (const int*)d_in[1];
    const float* W    = (const float*)d_in[2];
    const float* bias = (const float*)d_in[3];
    float* out = (float*)d_out;

    const size_t wb_bytes = (size_t)O_ * K_ * 2;            // 64 KB
    const size_t xb_bytes = (size_t)XELEMS * 2;             // 25.6 MB
    const size_t ctr_off  = wb_bytes + xb_bytes;            // 256-aligned
    unsigned short* Wb = (unsigned short*)d_ws;
    unsigned short* xb = (unsigned short*)((char*)d_ws + wb_bytes);
    unsigned int*  ctr = (unsigned int*)((char*)d_ws + ctr_off);

    const int grid_main = 8 * BPB; // 1568 blocks for the two-kernel path

    if (ws_size >= ctr_off + 32) {
        // Single-launch cooperative path: prep + grid.sync + spiral.
        void* args[8] = { (void*)&x, (void*)&adj, (void*)&W, (void*)&bias,
                          (void*)&out, (void*)&Wb, (void*)&xb, (void*)&ctr };
        hipError_t e = hipLaunchCooperativeKernel((const void*)fused_kernel,
                                                  dim3(GRID_COOP), dim3(256),
                                                  args, 0, stream);
        if (e == hipSuccess) return;
        (void)hipGetLastError(); // clear and fall through to two-kernel path
    }

    if (ws_size >= wb_bytes + xb_bytes) {
        int grid_prep = 128 + (XELEMS / 8 + 255) / 256; // 128 + 6250
        hipLaunchKernelGGL(prep_kernel, dim3(grid_prep), dim3(256), 0, stream, W, Wb, x, xb);
        hipLaunchKernelGGL(spiral_kernel, dim3(grid_main), dim3(256), 0, stream,
                           xb, adj, Wb, bias, out);
    } else {
        hipLaunchKernelGGL(wconv_kernel, dim3(128), dim3(256), 0, stream, W, Wb);
        hipLaunchKernelGGL(spiral_f32_kernel, dim3(grid_main), dim3(256), 0, stream,
                           x, adj, Wb, bias, out);
    }
}

// Round 6
// 232.849 us; speedup vs baseline: 1.7778x; 1.7778x over previous
//
#include <hip/hip_runtime.h>
#include <hip/hip_bf16.h>
#include <string.h>

#define B_ 8
#define N_ 50000
#define F_ 32
#define S_ 16
#define O_ 64
#define K_ (F_ * S_)            // 512
#define XELEMS (B_ * N_ * F_)   // 12.8M
#define TPB (N_ / 16)           // 3125 tiles per batch
#define BPB 196                 // blocks per batch (196*16 = 3136 >= 3125)

typedef __attribute__((ext_vector_type(8))) short bf16x8;
typedef __attribute__((ext_vector_type(4))) float f32x4;
typedef __attribute__((ext_vector_type(4))) int int4v;

union bfpack { bf16x8 v; __hip_bfloat16 h[8]; };

// ---- Prepass: W -> bf16 fragment-swizzled (64 KB) + x -> bf16 rows (25.6 MB) ----
// Wb[((kt*4 + quad)*64 + o)*8 + j] = bf16(W[o*512 + kt*32 + quad*8 + j])
__global__ __launch_bounds__(256) void prep_kernel(const float* __restrict__ W,
                                                   unsigned short* __restrict__ Wb,
                                                   const float* __restrict__ x,
                                                   unsigned short* __restrict__ xb) {
    int bid = blockIdx.x;
    if (bid < 128) {
        int i = bid * 256 + threadIdx.x; // [0, 32768)
        int j = i & 7;
        int o = (i >> 3) & 63;
        int qk = i >> 9;
        int quad = qk & 3;
        int kt = qk >> 2;
        __hip_bfloat16 h = __float2bfloat16(W[o * K_ + kt * 32 + quad * 8 + j]);
        unsigned short u; memcpy(&u, &h, 2);
        Wb[i] = u;
    } else {
        int i = (bid - 128) * 256 + threadIdx.x; // [0, 1.6M) groups of 8
        if (i < XELEMS / 8) {
            size_t base = (size_t)i * 8;
            f32x4 a = __builtin_nontemporal_load((const f32x4*)(x + base));
            f32x4 b = __builtin_nontemporal_load((const f32x4*)(x + base + 4));
            bfpack p;
            p.h[0] = __float2bfloat16(a[0]); p.h[1] = __float2bfloat16(a[1]);
            p.h[2] = __float2bfloat16(a[2]); p.h[3] = __float2bfloat16(a[3]);
            p.h[4] = __float2bfloat16(b[0]); p.h[5] = __float2bfloat16(b[1]);
            p.h[6] = __float2bfloat16(b[2]); p.h[7] = __float2bfloat16(b[3]);
            *(bf16x8*)(xb + base) = p.v;
        }
    }
}

// ---- Main kernel: LDS-DMA gathered GEMM with W resident in LDS ----
// r4 structure (VT=4, batch<->XCD partition, LDS-DMA gather ring, counted
// vmcnt, cached epilogue) with ONE change: the 64 KB Wb is staged into LDS
// once per block (global_load_lds x16/wave + one barrier) and W fragments
// are read via ds_read_b128. The K-loop's vmem path then carries ONLY the
// 4 scattered gathers per step (vmcnt 12/8/4/0) — W's ~16-32 segments/step
// move to the (idle) LDS pipe. LDS = 64K W + 64K ring = 128 KB -> 1 block/CU,
// 4 waves (r2 showed wave-count insensitivity). Ring is wave-private; the
// only barrier in the kernel is the post-stage W barrier.
__global__ __launch_bounds__(256, 1) void spiral_kernel(
        const unsigned short* __restrict__ xb, const int* __restrict__ adj,
        const unsigned short* __restrict__ Wb, const float* __restrict__ bias,
        float* __restrict__ out) {
    __shared__ __align__(16) unsigned short Wlds[32768];        // 64 KB, layout == Wb
    __shared__ __align__(16) unsigned char ring[4][4][4][1024]; // 64 KB gather ring

    const int lane = threadIdx.x & 63;
    const int wv   = threadIdx.x >> 6;
    const int m16  = lane & 15;
    const int quad = lane >> 4;

    const int b  = blockIdx.x & 7;   // batch == intended XCD
    const int jb = blockIdx.x >> 3;  // 0..195 block-within-batch
    const int tib0 = (jb * 4 + wv) * 4;

    unsigned char* ringw = &ring[wv][0][0][0];

    int rowbase[4], nn[4];
#pragma unroll
    for (int vt = 0; vt < 4; ++vt) {
        int t = tib0 + vt;
        if (t >= TPB) t = TPB - 1; // clamp within batch: duplicate identical stores, benign
        nn[vt] = t * 16;
        rowbase[vt] = b * N_ + t * 16;
    }
    const size_t xbase = (size_t)b * N_ * F_;

#define SB __builtin_amdgcn_sched_barrier(0)

    // --- Stage W into LDS: wave wv covers bytes [wv*16K, (wv+1)*16K), 16 x 1KB ---
#pragma unroll
    for (int i = 0; i < 16; ++i) {
        const unsigned short* src = Wb + (((size_t)wv * 16 + i) << 9) + lane * 8;
        __builtin_amdgcn_global_load_lds(
            (const __attribute__((address_space(1))) void*)src,
            (__attribute__((address_space(3))) void*)((unsigned char*)Wlds + (((wv * 16 + i)) << 10)),
            16, 0, 0);
    }
    SB;

    // --- All adj up front (nt: read-once stream). 16 x int4 = 64 VGPRs. ---
    int4v aj_all[4][4]; // [vt][kt4]
#pragma unroll
    for (int vt = 0; vt < 4; ++vt)
#pragma unroll
        for (int kt4 = 0; kt4 < 4; ++kt4)
            aj_all[vt][kt4] = __builtin_nontemporal_load(
                (const int4v*)(adj + (size_t)(rowbase[vt] + m16) * S_ + kt4 * 4));
    SB;

    f32x4 acc[4][4];
#pragma unroll
    for (int vt = 0; vt < 4; ++vt)
#pragma unroll
        for (int nt = 0; nt < 4; ++nt)
            acc[vt][nt] = (f32x4){0.f, 0.f, 0.f, 0.f};

    // Issue gathers for kt = g_ into ring slot g_&3 (4 LDS-DMA, one per vt).
#define GATHER_ISSUE(g_)                                                                   \
    do {                                                                                   \
        if ((g_) < 16) {                                                                   \
            const int kt4_ = (g_) >> 2, q_ = (g_) & 3;                                     \
            _Pragma("unroll")                                                              \
            for (int vt = 0; vt < 4; ++vt) {                                               \
                int a_ = aj_all[vt][kt4_][q_];                                             \
                const unsigned short* src_ = xb + xbase + (size_t)a_ * F_ + quad * 8;      \
                __builtin_amdgcn_global_load_lds(                                          \
                    (const __attribute__((address_space(1))) void*)src_,                   \
                    (__attribute__((address_space(3))) void*)(ringw + ((((g_) & 3) * 4 + vt) << 10)), \
                    16, 0, 0);                                                             \
            }                                                                              \
        }                                                                                  \
    } while (0)

    // Prologue: gathers for kt 0..2 behind the 16 W + 16 adj loads (in-order
    // retirement: vmcnt(12) drains W+adj+nothing-else, leaving g0..g2 in flight).
    GATHER_ISSUE(0); SB;
    GATHER_ISSUE(1); SB;
    GATHER_ISSUE(2); SB;
    asm volatile("s_waitcnt vmcnt(12)" ::: "memory"); // W + adj done; g0,g1,g2 in flight
    __syncthreads();                                  // W visible to all 4 waves

#pragma unroll
    for (int g = 0; g < 16; ++g) {
        GATHER_ISSUE(g + 3); SB;
        // Counted wait: slot g's 4 gathers done, 3 newer steps stay in flight.
        if (g < 13)       asm volatile("s_waitcnt vmcnt(12)" ::: "memory");
        else if (g == 13) asm volatile("s_waitcnt vmcnt(8)"  ::: "memory");
        else if (g == 14) asm volatile("s_waitcnt vmcnt(4)"  ::: "memory");
        else              asm volatile("s_waitcnt vmcnt(0)"  ::: "memory");
        SB;
        // Consume slot g&3 (ring) + W step g (LDS): 8 x ds_read_b128,
        // conflict-free (consecutive 8-lane groups tile all 32 banks).
        bf16x8 xf[4], wf[4];
#pragma unroll
        for (int vt = 0; vt < 4; ++vt)
            xf[vt] = *(const bf16x8*)(ringw + (((g & 3) * 4 + vt) << 10) + lane * 16);
#pragma unroll
        for (int nt = 0; nt < 4; ++nt)
            wf[nt] = *(const bf16x8*)(Wlds + (size_t)((g * 4 + quad) * 64 + nt * 16 + m16) * 8);
#pragma unroll
        for (int vt = 0; vt < 4; ++vt)
#pragma unroll
            for (int nt = 0; nt < 4; ++nt)
                // A = W-tile (m = o_local), B = x-tile (n = vertex)
                acc[vt][nt] = __builtin_amdgcn_mfma_f32_16x16x32_bf16(wf[nt], xf[vt], acc[vt][nt], 0, 0, 0);
        SB;
    }
#undef GATHER_ISSUE
#undef SB

    // Epilogue (cached stores: WRITE_SIZE exact at ~100 MB in r0/r4).
    // D layout: col = lane&15 = vertex, row = quad*4 + r = o within nt-tile.
#pragma unroll
    for (int vt = 0; vt < 4; ++vt) {
        const int n = nn[vt] + m16;
        const bool zero = (n == N_ - 1);
        float* orow = out + (size_t)(rowbase[vt] + m16) * O_ + quad * 4;
#pragma unroll
        for (int nt = 0; nt < 4; ++nt) {
            f32x4 bv = *(const f32x4*)(bias + nt * 16 + quad * 4);
            f32x4 v;
#pragma unroll
            for (int r = 0; r < 4; ++r) {
                float t = acc[vt][nt][r] + bv[r];
                t = t > 0.f ? t : (__expf(t) - 1.f); // ELU alpha=1
                v[r] = zero ? 0.f : t;
            }
            *(f32x4*)(orow + nt * 16) = v;
        }
    }
}

// ---- Fallback (ws too small): fp32-gather kernel ----
__global__ __launch_bounds__(256) void wconv_kernel(const float* __restrict__ W,
                                                    unsigned short* __restrict__ Wb) {
    int i = blockIdx.x * 256 + threadIdx.x;
    if (i < O_ * K_) {
        int j = i & 7, o = (i >> 3) & 63, qk = i >> 9;
        int quad = qk & 3, kt = qk >> 2;
        __hip_bfloat16 h = __float2bfloat16(W[o * K_ + kt * 32 + quad * 8 + j]);
        unsigned short u; memcpy(&u, &h, 2);
        Wb[i] = u;
    }
}

__global__ __launch_bounds__(256) void spiral_f32_kernel(
        const float* __restrict__ x, const int* __restrict__ adj,
        const unsigned short* __restrict__ Wb, const float* __restrict__ bias,
        float* __restrict__ out) {
    const int lane = threadIdx.x & 63;
    const int wv = threadIdx.x >> 6;
    const int m16 = lane & 15, quad = lane >> 4;
    const int b  = blockIdx.x & 7;
    const int jb = blockIdx.x >> 3;
    const int tib0 = (jb * 4 + wv) * 4;
    int rowbase[4], nn[4];
#pragma unroll
    for (int vt = 0; vt < 4; ++vt) {
        int t = tib0 + vt;
        if (t >= TPB) t = TPB - 1;
        nn[vt] = t * 16;
        rowbase[vt] = b * N_ + t * 16;
    }
    f32x4 acc[4][4];
#pragma unroll
    for (int vt = 0; vt < 4; ++vt)
#pragma unroll
        for (int nt = 0; nt < 4; ++nt) acc[vt][nt] = (f32x4){0.f,0.f,0.f,0.f};
    for (int kt = 0; kt < 16; ++kt) {
        bf16x8 wf[4];
#pragma unroll
        for (int nt = 0; nt < 4; ++nt)
            wf[nt] = *(const bf16x8*)(Wb + (size_t)((kt * 4 + quad) * 64 + nt * 16 + m16) * 8);
#pragma unroll
        for (int vt = 0; vt < 4; ++vt) {
            int a = adj[(size_t)(rowbase[vt] + m16) * S_ + kt];
            const float* xr = x + ((size_t)b * N_ + a) * F_ + quad * 8;
            f32x4 x0 = *(const f32x4*)xr;
            f32x4 x1 = *(const f32x4*)(xr + 4);
            bfpack af;
            af.h[0]=__float2bfloat16(x0[0]); af.h[1]=__float2bfloat16(x0[1]);
            af.h[2]=__float2bfloat16(x0[2]); af.h[3]=__float2bfloat16(x0[3]);
            af.h[4]=__float2bfloat16(x1[0]); af.h[5]=__float2bfloat16(x1[1]);
            af.h[6]=__float2bfloat16(x1[2]); af.h[7]=__float2bfloat16(x1[3]);
#pragma unroll
            for (int nt = 0; nt < 4; ++nt)
                acc[vt][nt] = __builtin_amdgcn_mfma_f32_16x16x32_bf16(wf[nt], af.v, acc[vt][nt], 0, 0, 0);
        }
    }
#pragma unroll
    for (int vt = 0; vt < 4; ++vt) {
        const int n = nn[vt] + m16;
        const bool zero = (n == N_ - 1);
        float* orow = out + (size_t)(rowbase[vt] + m16) * O_ + quad * 4;
#pragma unroll
        for (int nt = 0; nt < 4; ++nt) {
            f32x4 bv = *(const f32x4*)(bias + nt * 16 + quad * 4);
            f32x4 v;
#pragma unroll
            for (int r = 0; r < 4; ++r) {
                float t = acc[vt][nt][r] + bv[r];
                t = t > 0.f ? t : (__expf(t) - 1.f);
                v[r] = zero ? 0.f : t;
            }
            *(f32x4*)(orow + nt * 16) = v;
        }
    }
}

extern "C" void kernel_launch(void* const* d_in, const int* in_sizes, int n_in,
                              void* d_out, int out_size, void* d_ws, size_t ws_size,
                              hipStream_t stream) {
    const float* x    = (const float*)d_in[0];
    const int*   adj  = (const int*)d_in[1];
    const float* W    = (const float*)d_in[2];
    const float* bias = (const float*)d_in[3];
    float* out = (float*)d_out;

    const size_t wb_bytes = (size_t)O_ * K_ * 2;            // 64 KB
    const size_t xb_bytes = (size_t)XELEMS * 2;             // 25.6 MB
    unsigned short* Wb = (unsigned short*)d_ws;
    unsigned short* xb = (unsigned short*)((char*)d_ws + wb_bytes);

    const int grid_main = 8 * BPB; // 1568 blocks, batch = blockIdx % 8

    if (ws_size >= wb_bytes + xb_bytes) {
        int grid_prep = 128 + (XELEMS / 8 + 255) / 256; // 128 + 6250
        hipLaunchKernelGGL(prep_kernel, dim3(grid_prep), dim3(256), 0, stream, W, Wb, x, xb);
        hipLaunchKernelGGL(spiral_kernel, dim3(grid_main), dim3(256), 0, stream,
                           xb, adj, Wb, bias, out);
    } else {
        hipLaunchKernelGGL(wconv_kernel, dim3(128), dim3(256), 0, stream, W, Wb);
        hipLaunchKernelGGL(spiral_f32_kernel, dim3(grid_main), dim3(256), 0, stream,
                           x, adj, Wb, bias, out);
    }
}